// Round 11
// baseline (225.797 us; speedup 1.0000x reference)
//
#include <hip/hip_runtime.h>
#include <hip/hip_fp16.h>
#include <hip/hip_bf16.h>

#define NB 8
#define NC 64
#define NH 256
#define NW 512
#define ND 16
#define HW (NH * NW)          // 131072
#define EPSV 1e-6f
#define EXT 324               // 18x18 extended pixels
#define RSH 48                // LDS record stride in halves (96 B)

typedef __attribute__((ext_vector_type(8))) short bf16x8;
typedef __attribute__((ext_vector_type(4))) float f32x4;

__device__ __forceinline__ unsigned pack_bf16rn(float aa, float bb) {
    union { __hip_bfloat162 h2; unsigned u; } c;
    c.h2 = __float22bfloat162_rn(float2{aa, bb});
    return c.u;
}
__device__ __forceinline__ float fdot2f(unsigned ua, unsigned ub, float c) {
#if __has_builtin(__builtin_amdgcn_fdot2)
    typedef __attribute__((ext_vector_type(2))) _Float16 h2t;
    union { unsigned u; h2t h; } A, B;
    A.u = ua; B.u = ub;
    return __builtin_amdgcn_fdot2(A.h, B.h, c, false);
#else
    union { unsigned u; __half2 h; } A, B;
    A.u = ua; B.u = ub;
    float2 fa = __half22float2(A.h), fb = __half22float2(B.h);
    return fmaf(fa.y, fb.y, fmaf(fa.x, fb.x, c));
#endif
}

// ---------------------------------------------------------------------------
// Prep: pack wout (64x16 fp32) -> 512 half2 words in d_ws.
// ---------------------------------------------------------------------------
__global__ __launch_bounds__(512)
void wout_pack_kernel(const float* __restrict__ wout, unsigned* __restrict__ wopk)
{
    const int t = threadIdx.x;   // 0..511, one half2 word each
    union { __half2 h; unsigned u; } c;
    c.h = __floats2half2_rn(wout[2 * t], wout[2 * t + 1]);
    wopk[t] = c.u;
}

// ---------------------------------------------------------------------------
// Fully fused NA2D, v11. Block = 256 threads (4 waves), tile = 16x16.
// vs v10: (1) 256-thr blocks -> 5 independent blocks/CU (decorrelated
// barrier domains at same 62% occupancy); (2) phase 2 computed ONCE per
// pixel (no wave-pair duplication); (3) phase 3 = 8 fdot2/channel with
// packed-fp16 wout s_loaded from d_ws (uniform address -> scalar cache).
// ---------------------------------------------------------------------------
__global__ __launch_bounds__(256, 5)
void na2d_fused_v11(const float* __restrict__ x,
                    const float* __restrict__ wqkv,
                    const unsigned* __restrict__ wopk,
                    float* __restrict__ y)
{
    __shared__ __align__(16) __half s[EXT * RSH];   // 31104 B

    const int t    = threadIdx.x;
    const int wid  = t >> 6;
    const int lane = t & 63;
    const int lg   = lane >> 4;     // 0..3
    const int lr   = lane & 15;     // 0..15

    // XCD swizzle: each XCD owns one batch image -> halo reuse in its L2.
    const int wg = (blockIdx.x & 7) * 512 + (blockIdx.x >> 3);
    const int bx = wg & 31;
    const int by = (wg >> 5) & 15;
    const int b  = wg >> 9;
    const int w0 = bx * 16;
    const int h0 = by * 16;

    const float* __restrict__ xb = x + (size_t)b * NC * HW;

    // A fragments: wqkv rows, bf16-rn (24 VGPR resident)
    bf16x8 a[3][2];
    #pragma unroll
    for (int og = 0; og < 3; ++og) {
        const int row = og * 16 + lr;
        #pragma unroll
        for (int ks = 0; ks < 2; ++ks) {
            union { bf16x8 v; unsigned u[4]; } r;
            #pragma unroll
            for (int i = 0; i < 4; ++i)
                r.u[i] = pack_bf16rn(wqkv[row * NC + ks * 32 + lg * 8 + 2 * i],
                                     wqkv[row * NC + ks * 32 + lg * 8 + 2 * i + 1]);
            a[og][ks] = r.v;
        }
    }

    // ---- Phase 1: 4 waves x 6 pixel-groups (wave 3: tail-guarded) ----
    const int pb = wid * 96;

    #pragma unroll
    for (int pg = 0; pg < 6; ++pg) {
        if (pb + pg * 16 < EXT) {                  // wave-uniform
            const int pe = pb + pg * 16 + lr;
            const int ey = pe / 18;
            const int ex = pe - ey * 18;
            int hh = h0 + ey - 1;
            int ww = w0 + ex - 1;
            const bool valid = (unsigned)hh < NH && (unsigned)ww < NW;
            hh = hh < 0 ? 0 : (hh > NH - 1 ? NH - 1 : hh);   // clamp: safe addr,
            ww = ww < 0 ? 0 : (ww > NW - 1 ? NW - 1 : ww);   // zeroed at store
            const float* xp = xb + hh * NW + ww;

            float xv[16];
            #pragma unroll
            for (int j = 0; j < 16; ++j)
                xv[j] = xp[(size_t)((j >> 3) * 32 + lg * 8 + (j & 7)) * HW];

            union { bf16x8 v; unsigned u[4]; } bh[2];
            #pragma unroll
            for (int ks = 0; ks < 2; ++ks)
                #pragma unroll
                for (int i = 0; i < 4; ++i)
                    bh[ks].u[i] = pack_bf16rn(xv[ks * 8 + 2 * i], xv[ks * 8 + 2 * i + 1]);

            f32x4 acc[3];
            #pragma unroll
            for (int og = 0; og < 3; ++og) {
                acc[og] = (f32x4)(0.f);
                #pragma unroll
                for (int ks = 0; ks < 2; ++ks)
                    acc[og] = __builtin_amdgcn_mfma_f32_16x16x32_bf16(a[og][ks], bh[ks].v, acc[og], 0, 0, 0);
            }

            if (pe < EXT) {                        // per-lane tail (wave 3)
                #pragma unroll
                for (int og = 0; og < 3; ++og) {
                    f32x4 v = acc[og];
                    if (og < 2) {                  // phi = elu + 1 on q,k
                        #pragma unroll
                        for (int i = 0; i < 4; ++i)
                            v[i] = v[i] > 0.f ? v[i] + 1.f : __expf(v[i]);
                    }
                    if (!valid) v = (f32x4)(0.f);  // zero-pad AFTER phi
                    union { uint2 d; struct { __half2 a2, b2; } h; } pk;
                    pk.h.a2 = __floats2half2_rn(v[0], v[1]);
                    pk.h.b2 = __floats2half2_rn(v[2], v[3]);
                    *reinterpret_cast<uint2*>(&s[pe * RSH + og * 16 + lg * 4]) = pk.d;
                }
            }
        }
    }
    __syncthreads();

    // ---- Phase 2: attention, one pixel per thread (no duplication) ----
    const int py = t >> 4, px = t & 15;

    uint4 q0, q1;
    {
        const __half* qp = &s[((py + 1) * 18 + (px + 1)) * RSH];
        q0 = *reinterpret_cast<const uint4*>(qp);
        q1 = *reinterpret_cast<const uint4*>(qp + 8);
    }

    float sc[9];
    float ssum = 0.f;
    #pragma unroll
    for (int n = 0; n < 9; ++n) {
        const int r = (py + n / 3) * 18 + (px + n % 3);
        const __half* kp = &s[r * RSH + 16];
        const uint4 k0 = *reinterpret_cast<const uint4*>(kp);
        const uint4 k1 = *reinterpret_cast<const uint4*>(kp + 8);
        float sv = 0.f;
        sv = fdot2f(q0.x, k0.x, sv);
        sv = fdot2f(q0.y, k0.y, sv);
        sv = fdot2f(q0.z, k0.z, sv);
        sv = fdot2f(q0.w, k0.w, sv);
        sv = fdot2f(q1.x, k1.x, sv);
        sv = fdot2f(q1.y, k1.y, sv);
        sv = fdot2f(q1.z, k1.z, sv);
        sv = fdot2f(q1.w, k1.w, sv);
        sc[n] = sv;
        ssum += sv;
    }
    const float inv = 1.f / (ssum + EPSV);

    union { __half2 h[8]; unsigned u[8]; } ov;
    #pragma unroll
    for (int i = 0; i < 8; ++i) ov.h[i] = __half2half2(__float2half_rn(0.f));
    #pragma unroll
    for (int n = 0; n < 9; ++n) {
        const int r = (py + n / 3) * 18 + (px + n % 3);
        const __half* vp = &s[r * RSH + 32];
        union { uint4 u; __half2 h[4]; } v0, v1;
        v0.u = *reinterpret_cast<const uint4*>(vp);
        v1.u = *reinterpret_cast<const uint4*>(vp + 8);
        const __half2 wn2 = __half2half2(__float2half_rn(sc[n] * inv));
        #pragma unroll
        for (int i = 0; i < 4; ++i) ov.h[i]     = __hfma2(wn2, v0.h[i], ov.h[i]);
        #pragma unroll
        for (int i = 0; i < 4; ++i) ov.h[4 + i] = __hfma2(wn2, v1.h[i], ov.h[4 + i]);
    }

    // ---- Phase 3: out-projection, 64 channels, 8 fdot2 each ----
    // wopk is uniform-indexed -> s_load into SGPRs, scalar cache resident.
    const int h = h0 + py, w = w0 + px;
    float* yp = y + (size_t)b * NC * HW + h * NW + w;
    #pragma unroll 8
    for (int o = 0; o < NC; ++o) {
        float a2 = 0.f;
        #pragma unroll
        for (int i = 0; i < 8; ++i)
            a2 = fdot2f(wopk[o * 8 + i], ov.u[i], a2);
        yp[(size_t)o * HW] = a2;
    }
}

extern "C" void kernel_launch(void* const* d_in, const int* in_sizes, int n_in,
                              void* d_out, int out_size, void* d_ws, size_t ws_size,
                              hipStream_t stream)
{
    const float* x    = (const float*)d_in[0];
    const float* wqkv = (const float*)d_in[1];
    const float* wout = (const float*)d_in[2];
    float* y = (float*)d_out;
    unsigned* wopk = (unsigned*)d_ws;   // 512 u32 = 2 KB

    wout_pack_kernel<<<1, 512, 0, stream>>>(wout, wopk);
    const int nblocks = (NW / 16) * (NH / 16) * NB;   // 4096
    na2d_fused_v11<<<nblocks, 256, 0, stream>>>(x, wqkv, wopk, y);
}

// Round 12
// 225.796 us; speedup vs baseline: 1.0000x; 1.0000x over previous
//
#include <hip/hip_runtime.h>
#include <hip/hip_fp16.h>
#include <hip/hip_bf16.h>

#define NB 8
#define NC 64
#define NH 256
#define NW 512
#define ND 16
#define HW (NH * NW)          // 131072
#define EPSV 1e-6f
#define EXT 324               // 18x18 extended pixels
#define RSH 48                // record stride in halves (96 B = 6 uint4)

typedef __attribute__((ext_vector_type(8))) short bf16x8;
typedef __attribute__((ext_vector_type(4))) float f32x4;

__device__ __forceinline__ unsigned pack_bf16rn(float aa, float bb) {
    union { __hip_bfloat162 h2; unsigned u; } c;
    c.h2 = __float22bfloat162_rn(float2{aa, bb});
    return c.u;
}
__device__ __forceinline__ float fdot2f(unsigned ua, unsigned ub, float c) {
#if __has_builtin(__builtin_amdgcn_fdot2)
    typedef __attribute__((ext_vector_type(2))) _Float16 h2t;
    union { unsigned u; h2t h; } A, B;
    A.u = ua; B.u = ub;
    return __builtin_amdgcn_fdot2(A.h, B.h, c, false);
#else
    union { unsigned u; __half2 h; } A, B;
    A.u = ua; B.u = ub;
    float2 fa = __half22float2(A.h), fb = __half22float2(B.h);
    return fmaf(fa.y, fb.y, fmaf(fa.x, fb.x, c));
#endif
}

// ---------------------------------------------------------------------------
// Prep: pack wout (64x16 fp32) -> 512 half2 words.
// ---------------------------------------------------------------------------
__global__ __launch_bounds__(512)
void wout_pack_kernel(const float* __restrict__ wout, unsigned* __restrict__ wopk)
{
    const int t = threadIdx.x;
    union { __half2 h; unsigned u; } c;
    c.h = __floats2half2_rn(wout[2 * t], wout[2 * t + 1]);
    wopk[t] = c.u;
}

// ---------------------------------------------------------------------------
// K1: qkv projection (MFMA, W & x bf16-rn) + phi -> fp16 records (global).
// Wave computes 48 ch x 64 px; LDS transpose -> contiguous 96 B records.
// ---------------------------------------------------------------------------
__global__ __launch_bounds__(256, 6)
void k1_qkv_proj(const float* __restrict__ x,
                 const float* __restrict__ wqkv,
                 __half* __restrict__ qkv)
{
    __shared__ __align__(16) __half st[256 * RSH];   // 24576 B

    const int t    = threadIdx.x;
    const int wid  = t >> 6;
    const int lane = t & 63;
    const int lg   = lane >> 4;
    const int lr   = lane & 15;

    const int gp0 = blockIdx.x * 256 + wid * 64;   // wave's first pixel
    const int b   = gp0 >> 17;
    const int p0  = gp0 & (HW - 1);
    const float* __restrict__ xb = x + (size_t)b * NC * HW;

    // A fragments: wqkv rows, bf16-rn
    bf16x8 a[3][2];
    #pragma unroll
    for (int og = 0; og < 3; ++og) {
        const int row = og * 16 + lr;
        #pragma unroll
        for (int ks = 0; ks < 2; ++ks) {
            union { bf16x8 v; unsigned u[4]; } r;
            #pragma unroll
            for (int i = 0; i < 4; ++i)
                r.u[i] = pack_bf16rn(wqkv[row * NC + ks * 32 + lg * 8 + 2 * i],
                                     wqkv[row * NC + ks * 32 + lg * 8 + 2 * i + 1]);
            a[og][ks] = r.v;
        }
    }

    #pragma unroll
    for (int pg = 0; pg < 4; ++pg) {
        const int p = p0 + pg * 16 + lr;

        float xv[16];
        #pragma unroll
        for (int j = 0; j < 16; ++j)
            xv[j] = xb[(size_t)((j >> 3) * 32 + lg * 8 + (j & 7)) * HW + p];

        union { bf16x8 v; unsigned u[4]; } bh[2];
        #pragma unroll
        for (int ks = 0; ks < 2; ++ks)
            #pragma unroll
            for (int i = 0; i < 4; ++i)
                bh[ks].u[i] = pack_bf16rn(xv[ks * 8 + 2 * i], xv[ks * 8 + 2 * i + 1]);

        f32x4 acc[3];
        #pragma unroll
        for (int og = 0; og < 3; ++og) {
            acc[og] = (f32x4)(0.f);
            #pragma unroll
            for (int ks = 0; ks < 2; ++ks)
                acc[og] = __builtin_amdgcn_mfma_f32_16x16x32_bf16(a[og][ks], bh[ks].v, acc[og], 0, 0, 0);
        }

        // phi on q,k; fp16 pack; transpose via LDS
        // D layout: pixel = lr (col), channel = og*16 + lg*4 + i (row)
        #pragma unroll
        for (int og = 0; og < 3; ++og) {
            f32x4 v = acc[og];
            if (og < 2) {
                #pragma unroll
                for (int i = 0; i < 4; ++i)
                    v[i] = v[i] > 0.f ? v[i] + 1.f : __expf(v[i]);
            }
            union { uint2 d; struct { __half2 a2, b2; } h; } pk;
            pk.h.a2 = __floats2half2_rn(v[0], v[1]);
            pk.h.b2 = __floats2half2_rn(v[2], v[3]);
            *reinterpret_cast<uint2*>(&st[(wid * 64 + pg * 16 + lr) * RSH + og * 16 + lg * 4]) = pk.d;
        }
    }
    __syncthreads();

    // contiguous 96 B record store (thread t -> pixel blk*256+t)
    uint4* dst = reinterpret_cast<uint4*>(qkv) + ((size_t)blockIdx.x * 256 + t) * 6;
    const uint4* src = reinterpret_cast<const uint4*>(&st[t * RSH]);
    #pragma unroll
    for (int i = 0; i < 6; ++i) dst[i] = src[i];
}

// ---------------------------------------------------------------------------
// K2: stage 18x18 records -> LDS, attention (fdot2/hfma2), out-proj (fdot2
// with packed-fp16 wout via scalar cache).
// ---------------------------------------------------------------------------
__global__ __launch_bounds__(256, 5)
void k2_attn_out(const __half* __restrict__ qkv,
                 const unsigned* __restrict__ wopk,
                 float* __restrict__ y)
{
    __shared__ __align__(16) __half s[EXT * RSH];   // 31104 B

    const int t = threadIdx.x;

    // XCD swizzle: each XCD owns one batch image.
    const int wg = (blockIdx.x & 7) * 512 + (blockIdx.x >> 3);
    const int bx = wg & 31;
    const int by = (wg >> 5) & 15;
    const int b  = wg >> 9;
    const int w0 = bx * 16;
    const int h0 = by * 16;

    const uint4* __restrict__ qb = reinterpret_cast<const uint4*>(qkv) + (size_t)b * HW * 6;

    // stage 324 records x 6 uint4 (zero OOB)
    for (int i = t; i < EXT * 6; i += 256) {
        const int r  = i / 6;
        const int j  = i - r * 6;
        const int ey = r / 18;
        const int ex = r - ey * 18;
        const int hh = h0 + ey - 1;
        const int ww = w0 + ex - 1;
        uint4 val = make_uint4(0u, 0u, 0u, 0u);
        if ((unsigned)hh < NH && (unsigned)ww < NW)
            val = qb[(size_t)(hh * NW + ww) * 6 + j];
        *reinterpret_cast<uint4*>(&s[r * RSH + j * 8]) = val;
    }
    __syncthreads();

    const int py = t >> 4, px = t & 15;

    uint4 q0, q1;
    {
        const __half* qp = &s[((py + 1) * 18 + (px + 1)) * RSH];
        q0 = *reinterpret_cast<const uint4*>(qp);
        q1 = *reinterpret_cast<const uint4*>(qp + 8);
    }

    float sc[9];
    float ssum = 0.f;
    #pragma unroll
    for (int n = 0; n < 9; ++n) {
        const int r = (py + n / 3) * 18 + (px + n % 3);
        const __half* kp = &s[r * RSH + 16];
        const uint4 k0 = *reinterpret_cast<const uint4*>(kp);
        const uint4 k1 = *reinterpret_cast<const uint4*>(kp + 8);
        float sv = 0.f;
        sv = fdot2f(q0.x, k0.x, sv);
        sv = fdot2f(q0.y, k0.y, sv);
        sv = fdot2f(q0.z, k0.z, sv);
        sv = fdot2f(q0.w, k0.w, sv);
        sv = fdot2f(q1.x, k1.x, sv);
        sv = fdot2f(q1.y, k1.y, sv);
        sv = fdot2f(q1.z, k1.z, sv);
        sv = fdot2f(q1.w, k1.w, sv);
        sc[n] = sv;
        ssum += sv;
    }
    const float inv = 1.f / (ssum + EPSV);

    union { __half2 h[8]; unsigned u[8]; } ov;
    #pragma unroll
    for (int i = 0; i < 8; ++i) ov.h[i] = __half2half2(__float2half_rn(0.f));
    #pragma unroll
    for (int n = 0; n < 9; ++n) {
        const int r = (py + n / 3) * 18 + (px + n % 3);
        const __half* vp = &s[r * RSH + 32];
        union { uint4 u; __half2 h[4]; } v0, v1;
        v0.u = *reinterpret_cast<const uint4*>(vp);
        v1.u = *reinterpret_cast<const uint4*>(vp + 8);
        const __half2 wn2 = __half2half2(__float2half_rn(sc[n] * inv));
        #pragma unroll
        for (int i = 0; i < 4; ++i) ov.h[i]     = __hfma2(wn2, v0.h[i], ov.h[i]);
        #pragma unroll
        for (int i = 0; i < 4; ++i) ov.h[4 + i] = __hfma2(wn2, v1.h[i], ov.h[4 + i]);
    }

    const int h = h0 + py, w = w0 + px;
    float* yp = y + (size_t)b * NC * HW + h * NW + w;
    #pragma unroll 8
    for (int o = 0; o < NC; ++o) {
        float a2 = 0.f;
        #pragma unroll
        for (int i = 0; i < 8; ++i)
            a2 = fdot2f(wopk[o * 8 + i], ov.u[i], a2);
        yp[(size_t)o * HW] = a2;
    }
}

extern "C" void kernel_launch(void* const* d_in, const int* in_sizes, int n_in,
                              void* d_out, int out_size, void* d_ws, size_t ws_size,
                              hipStream_t stream)
{
    const float* x    = (const float*)d_in[0];
    const float* wqkv = (const float*)d_in[1];
    const float* wout = (const float*)d_in[2];
    float* y = (float*)d_out;

    unsigned* wopk = (unsigned*)d_ws;                       // 2 KB
    __half*   qkv  = (__half*)((char*)d_ws + 4096);         // 100.7 MB

    wout_pack_kernel<<<1, 512, 0, stream>>>(wout, wopk);

    const int npix = NB * HW;
    k1_qkv_proj<<<npix / 256, 256, 0, stream>>>(x, wqkv, qkv);

    const int nblocks = (NW / 16) * (NH / 16) * NB;         // 4096
    k2_attn_out<<<nblocks, 256, 0, stream>>>(qkv, wopk, y);
}